// Round 14
// baseline (238.611 us; speedup 1.0000x reference)
//
#include <hip/hip_runtime.h>
#include <hip/hip_bf16.h>
#include <math.h>

namespace {
constexpr int Hn  = 16;    // heads
constexpr int DH  = 64;    // head dim
constexpr int S   = 2048;  // seq
constexpr int D   = 1024;  // model dim
constexpr int B   = 2;     // batch
constexpr int N   = B * S; // 4096 rows
}

typedef __attribute__((ext_vector_type(8))) short bf16x8;
typedef __attribute__((ext_vector_type(4))) float f32x4;

#if defined(__has_builtin)
#if __has_builtin(__builtin_amdgcn_exp2f)
#define HAVE_EXP2_BUILTIN 1
#endif
#endif

static __device__ __forceinline__ float exp2_fast(float x) {
#ifdef HAVE_EXP2_BUILTIN
    return __builtin_amdgcn_exp2f(x);
#else
    float r;
    asm("v_exp_f32 %0, %1" : "=v"(r) : "v"(x));
    return r;
#endif
}

static __device__ __forceinline__ ushort bf16rd(float x) {
    unsigned u = __builtin_bit_cast(unsigned, x);
    return (ushort)((u + 0x8000u) >> 16);
}
static __device__ __forceinline__ float bfu2f(ushort h) {
    unsigned u = (unsigned)h << 16;
    return __builtin_bit_cast(float, u);
}
static __device__ __forceinline__ void split1(float a, ushort& h, ushort& l) {
    h = bf16rd(a);
    l = bf16rd(a - bfu2f(h));
}

// async global->LDS, 16B per lane
static __device__ __forceinline__ void gload16(const ushort* g, ushort* l) {
    __builtin_amdgcn_global_load_lds((const unsigned int*)g, (unsigned int*)l, 16, 0, 0);
}

// ---------------------------------------------------------------------------
// One launch, all conversions: q,k,v -> bf16 hi; Wq,Wk,Wv -> hi; Wo -> hi/lo.
// ---------------------------------------------------------------------------
__global__ __launch_bounds__(256) void split_all(
    const float4* __restrict__ q, const float4* __restrict__ k, const float4* __restrict__ v,
    const float4* __restrict__ wq, const float4* __restrict__ wk,
    const float4* __restrict__ wv, const float4* __restrict__ wo,
    ushort4* __restrict__ qh, ushort4* __restrict__ kh, ushort4* __restrict__ vh,
    ushort4* __restrict__ wqh, ushort4* __restrict__ wkh, ushort4* __restrict__ wvh,
    ushort4* __restrict__ woh, ushort4* __restrict__ wol,
    int n4a, int n4w) {
    const int total = 3 * n4a + 4 * n4w;
    const int stride = gridDim.x * 256;
    for (int i = blockIdx.x * 256 + threadIdx.x; i < total; i += stride) {
        if (i < 3 * n4a) {
            const int which = i / n4a;
            const int j = i - which * n4a;
            const float4 val = (which == 0 ? q : which == 1 ? k : v)[j];
            ushort4* ph = which == 0 ? qh : which == 1 ? kh : vh;
            ph[j] = make_ushort4(bf16rd(val.x), bf16rd(val.y), bf16rd(val.z), bf16rd(val.w));
        } else {
            const int t = i - 3 * n4a;
            const int which = t / n4w;
            const int j = t - which * n4w;
            const float4 val = (which == 0 ? wq : which == 1 ? wk : which == 2 ? wv : wo)[j];
            if (which == 3) {
                ushort4 hh, ll;
                split1(val.x, hh.x, ll.x);
                split1(val.y, hh.y, ll.y);
                split1(val.z, hh.z, ll.z);
                split1(val.w, hh.w, ll.w);
                woh[j] = hh;
                wol[j] = ll;
            } else {
                ushort4* ph = which == 0 ? wqh : which == 1 ? wkh : wvh;
                ph[j] = make_ushort4(bf16rd(val.x), bf16rd(val.y), bf16rd(val.z), bf16rd(val.w));
            }
        }
    }
}

// ---------------------------------------------------------------------------
// Merged Q/K/V projection (r10-verified): 1-pass bf16, BK=64, single LDS
// buffer, global_load_lds staging (pre-swizzled source, swizzled ds_read),
// 2 barriers per K-step. Grid 32 x 24; which: 0->Q(scaled) 1->K 2->V^T.
// V^T store applies the pos<->kv permutation (kv=16a+4g+r -> pos=8g+4a+r).
// ---------------------------------------------------------------------------
__global__ __launch_bounds__(256) void gemm_qkv(
    const ushort* __restrict__ qbf, const ushort* __restrict__ kbf,
    const ushort* __restrict__ vbf,
    const ushort* __restrict__ Wqh, const ushort* __restrict__ Wkh,
    const ushort* __restrict__ Wvh,
    ushort* __restrict__ Qbh, ushort* __restrict__ Kbh,
    ushort* __restrict__ Vtb, float qscale) {
    constexpr int BK = 64;   // 128 B rows, 8 chunks of 16 B
    constexpr int K = D;
    __shared__ __align__(16) ushort sA[128 * BK];
    __shared__ __align__(16) ushort sB[128 * BK];

    const int tid = threadIdx.x;
    const int which = blockIdx.y >> 3;
    const int m0 = blockIdx.x * 128;
    const int n0 = (blockIdx.y & 7) * 128;

    const ushort* A = which == 0 ? qbf : which == 1 ? kbf : vbf;
    const ushort* W = which == 0 ? Wqh : which == 1 ? Wkh : Wvh;

    const int l  = tid & 63;
    const int w  = tid >> 6;
    const int wm = w >> 1, wn = w & 1;
    const int lm = l & 15, g = l >> 4;

    const int srow = l >> 3;                 // 0..7
    const int schunk = (l & 7) ^ srow;       // pre-swizzled source chunk
    const ushort* gA = A + (size_t)(m0 + w * 32 + srow) * K + schunk * 8;
    const ushort* gB = W + (size_t)(n0 + w * 32 + srow) * K + schunk * 8;
    ushort* lA = &sA[(w * 32) * BK];
    ushort* lB = &sB[(w * 32) * BK];

    const f32x4 fzero = {0.f, 0.f, 0.f, 0.f};
    f32x4 acc[4][4];
#pragma unroll
    for (int mi = 0; mi < 4; ++mi)
#pragma unroll
        for (int ni = 0; ni < 4; ++ni) acc[mi][ni] = fzero;

    const int rsw = lm & 7;  // read-side swizzle

    for (int s = 0; s < K / BK; ++s) {
        const int k0 = s * BK;
        if (s) __syncthreads();
#pragma unroll
        for (int j = 0; j < 4; ++j) {
            gload16(gA + (size_t)(j * 8) * K + k0, lA + (j * 8) * BK);
            gload16(gB + (size_t)(j * 8) * K + k0, lB + (j * 8) * BK);
        }
        __syncthreads();

#pragma unroll
        for (int kk = 0; kk < 2; ++kk) {
            bf16x8 ah[4], bh[4];
#pragma unroll
            for (int mi = 0; mi < 4; ++mi)
                ah[mi] = *(const bf16x8*)&sA[(wm * 64 + mi * 16 + lm) * BK + (((kk * 4 + g) ^ rsw) * 8)];
#pragma unroll
            for (int ni = 0; ni < 4; ++ni)
                bh[ni] = *(const bf16x8*)&sB[(wn * 64 + ni * 16 + lm) * BK + (((kk * 4 + g) ^ rsw) * 8)];
            __builtin_amdgcn_s_setprio(1);
#pragma unroll
            for (int mi = 0; mi < 4; ++mi)
#pragma unroll
                for (int ni = 0; ni < 4; ++ni)
                    acc[mi][ni] = __builtin_amdgcn_mfma_f32_16x16x32_bf16(
                        ah[mi], bh[ni], acc[mi][ni], 0, 0, 0);
            __builtin_amdgcn_s_setprio(0);
        }
    }

#pragma unroll
    for (int mi = 0; mi < 4; ++mi)
#pragma unroll
        for (int ni = 0; ni < 4; ++ni) {
            const int col = n0 + wn * 64 + ni * 16 + lm;
            const int rbase = m0 + wm * 64 + mi * 16 + g * 4;
            const int hh = col >> 6, dh = col & (DH - 1);
            if (which == 0) {  // Q: scaled, hi
#pragma unroll
                for (int r = 0; r < 4; ++r) {
                    const int row = rbase + r;
                    const int bb = row >> 11, ss = row & (S - 1);
                    const size_t idx = (((size_t)(bb * Hn + hh)) * S + ss) * DH + dh;
                    Qbh[idx] = bf16rd(acc[mi][ni][r] * qscale);
                }
            } else if (which == 1) {  // K: hi
#pragma unroll
                for (int r = 0; r < 4; ++r) {
                    const int row = rbase + r;
                    const int bb = row >> 11, ss = row & (S - 1);
                    const size_t idx = (((size_t)(bb * Hn + hh)) * S + ss) * DH + dh;
                    Kbh[idx] = bf16rd(acc[mi][ni][r]);
                }
            } else {  // V^T: hi, transposed + pos-permuted store
                const int bb = rbase >> 11, ss = rbase & (S - 1);
                const int ssp = (ss & ~31) | (((ss >> 2) & 3) << 3) | (((ss >> 4) & 1) << 2);
                ushort4 pk;
                pk.x = bf16rd(acc[mi][ni][0]);
                pk.y = bf16rd(acc[mi][ni][1]);
                pk.z = bf16rd(acc[mi][ni][2]);
                pk.w = bf16rd(acc[mi][ni][3]);
                const size_t idx = (((size_t)(bb * Hn + hh)) * DH + dh) * S + ssp;
                *(ushort4*)&Vtb[idx] = pk;
            }
        }
}

// ---------------------------------------------------------------------------
// Output projection GEMM: 3-pass split-bf16, fp32 store, NOW with the
// qkv-proven staging: gload_lds BK=64, pre-swizzled source + swizzled b128
// reads, single 48 KB LDS buffer, 2 barriers per K-step, 48 MFMA/step/wave.
// ---------------------------------------------------------------------------
__global__ __launch_bounds__(256) void gemm_out(const ushort* __restrict__ Ah,
                                                const ushort* __restrict__ Al,
                                                const ushort* __restrict__ Wh,
                                                const ushort* __restrict__ Wl,
                                                float* __restrict__ C) {
    constexpr int BK = 64;
    constexpr int K = D, O = D;
    __shared__ __align__(16) ushort sAh[128 * BK];
    __shared__ __align__(16) ushort sAl[128 * BK];
    __shared__ __align__(16) ushort sBh[64 * BK];
    __shared__ __align__(16) ushort sBl[64 * BK];

    const int tid = threadIdx.x;
    const int m0 = blockIdx.x * 128;
    const int n0 = blockIdx.y * 64;

    const int l  = tid & 63;
    const int w  = tid >> 6;
    const int wm = w >> 1, wn = w & 1;
    const int lm = l & 15, g = l >> 4;

    const int srow = l >> 3;
    const int schunk = (l & 7) ^ srow;
    const ushort* gAh = Ah + (size_t)(m0 + w * 32 + srow) * K + schunk * 8;
    const ushort* gAl = Al + (size_t)(m0 + w * 32 + srow) * K + schunk * 8;
    const ushort* gBh = Wh + (size_t)(n0 + w * 16 + srow) * K + schunk * 8;
    const ushort* gBl = Wl + (size_t)(n0 + w * 16 + srow) * K + schunk * 8;
    ushort* lAh = &sAh[(w * 32) * BK];
    ushort* lAl = &sAl[(w * 32) * BK];
    ushort* lBh = &sBh[(w * 16) * BK];
    ushort* lBl = &sBl[(w * 16) * BK];

    const f32x4 fzero = {0.f, 0.f, 0.f, 0.f};
    f32x4 acc[4][2];
#pragma unroll
    for (int mi = 0; mi < 4; ++mi)
#pragma unroll
        for (int ni = 0; ni < 2; ++ni) acc[mi][ni] = fzero;

    const int rsw = lm & 7;

    for (int s = 0; s < K / BK; ++s) {
        const int k0 = s * BK;
        if (s) __syncthreads();
#pragma unroll
        for (int j = 0; j < 4; ++j) {
            gload16(gAh + (size_t)(j * 8) * K + k0, lAh + (j * 8) * BK);
            gload16(gAl + (size_t)(j * 8) * K + k0, lAl + (j * 8) * BK);
        }
#pragma unroll
        for (int j = 0; j < 2; ++j) {
            gload16(gBh + (size_t)(j * 8) * K + k0, lBh + (j * 8) * BK);
            gload16(gBl + (size_t)(j * 8) * K + k0, lBl + (j * 8) * BK);
        }
        __syncthreads();

#pragma unroll
        for (int kk = 0; kk < 2; ++kk) {
            const int rc = ((kk * 4 + g) ^ rsw) * 8;
            bf16x8 ah[4], al[4], bh[2], bl[2];
#pragma unroll
            for (int mi = 0; mi < 4; ++mi) {
                const int row = wm * 64 + mi * 16 + lm;
                ah[mi] = *(const bf16x8*)&sAh[row * BK + rc];
                al[mi] = *(const bf16x8*)&sAl[row * BK + rc];
            }
#pragma unroll
            for (int ni = 0; ni < 2; ++ni) {
                const int rowb = wn * 32 + ni * 16 + lm;
                bh[ni] = *(const bf16x8*)&sBh[rowb * BK + rc];
                bl[ni] = *(const bf16x8*)&sBl[rowb * BK + rc];
            }
            __builtin_amdgcn_s_setprio(1);
#pragma unroll
            for (int mi = 0; mi < 4; ++mi)
#pragma unroll
                for (int ni = 0; ni < 2; ++ni) {
                    acc[mi][ni] = __builtin_amdgcn_mfma_f32_16x16x32_bf16(
                        al[mi], bh[ni], acc[mi][ni], 0, 0, 0);
                    acc[mi][ni] = __builtin_amdgcn_mfma_f32_16x16x32_bf16(
                        ah[mi], bl[ni], acc[mi][ni], 0, 0, 0);
                    acc[mi][ni] = __builtin_amdgcn_mfma_f32_16x16x32_bf16(
                        ah[mi], bh[ni], acc[mi][ni], 0, 0, 0);
                }
            __builtin_amdgcn_s_setprio(0);
        }
    }

#pragma unroll
    for (int mi = 0; mi < 4; ++mi)
#pragma unroll
        for (int ni = 0; ni < 2; ++ni) {
            const int col = n0 + wn * 32 + ni * 16 + lm;
            const int rbase = m0 + wm * 64 + mi * 16 + g * 4;
#pragma unroll
            for (int r = 0; r < 4; ++r)
                C[(size_t)(rbase + r) * O + col] = acc[mi][ni][r];
        }
}

// ---------------------------------------------------------------------------
// Split-KV MFMA flash attention, in-register P (r13-verified math), now with
// 256-thr blocks: 2 q-waves (64 q-rows) x 2 KV-parity groups -> grid 1024 =
// 4 blocks/CU (4 independent barrier domains). Swapped QK^T + pos-permuted
// V^T global layout; P never touches LDS. 36.9 KB LDS pool, reused for the
// end-of-kernel group combine.
// ---------------------------------------------------------------------------
__global__ __launch_bounds__(256) void attn_mfma(const ushort* __restrict__ Qbh,
                                                 const ushort* __restrict__ Kbh,
                                                 const ushort* __restrict__ Vt,
                                                 ushort* __restrict__ AOh,
                                                 ushort* __restrict__ AOl) {
    constexpr int LDT = 72;
    __shared__ __align__(16) ushort pool[4 * 64 * LDT];  // 36,864 B

    const int tid = threadIdx.x;
    const int l = tid & 63, w = tid >> 6;   // w 0..3
    const int wq = w & 1, grp = w >> 1;     // q-wave slot, kv parity group
    const int g = l >> 4, l15 = l & 15;
    const int bh = blockIdx.x;
    const int q0 = blockIdx.y * 64;
    const size_t bhb = (size_t)bh * S * DH;

    ushort* Ksg = pool + grp * (64 * LDT);
    ushort* Vsg = pool + (2 + grp) * (64 * LDT);

    // Q fragments (log2e/8 folded in at projection); rows q0 + wq*32 + ...
    bf16x8 qh_[2][2];
#pragma unroll
    for (int qb = 0; qb < 2; ++qb)
#pragma unroll
        for (int kk = 0; kk < 2; ++kk) {
            const size_t idx = bhb + (size_t)(q0 + wq * 32 + qb * 16 + l15) * DH + kk * 32 + g * 8;
            qh_[qb][kk] = *(const bf16x8*)(Qbh + idx);
        }

    // staging: each group = 128 threads; thread -> row t7>>1, 64B half (t7&1)
    const int t7 = tid & 127;
    const int r_st = t7 >> 1;
    const int c0 = (t7 & 1) * 32;
    const ushort* gKh = Kbh + bhb + (size_t)r_st * DH + c0;
    const ushort* gVt = Vt + (size_t)bh * DH * S + (size_t)r_st * S + c0;

    const f32x4 fzero = {0.f, 0.f, 0.f, 0.f};
    f32x4 o_acc[2][4];
    f32x4 l_acc[2];
#pragma unroll
    for (int qb = 0; qb < 2; ++qb) {
        l_acc[qb] = fzero;
#pragma unroll
        for (int f = 0; f < 4; ++f) o_acc[qb][f] = fzero;
    }

    bf16x8 ones;
#pragma unroll
    for (int i = 0; i < 8; ++i) ones[i] = (short)0x3F80;

    // prologue: tile grp -> LDS; tile 2+grp -> regs
    uint4 pk[4], pv[4];
    {
        const size_t ok = (size_t)grp * 64 * DH, ov = (size_t)grp * 64;
#pragma unroll
        for (int j = 0; j < 4; ++j) {
            pk[j] = *(const uint4*)(gKh + ok + j * 8);
            pv[j] = *(const uint4*)(gVt + ov + j * 8);
        }
#pragma unroll
        for (int j = 0; j < 4; ++j) {
            *(uint4*)&Ksg[r_st * LDT + c0 + j * 8] = pk[j];
            *(uint4*)&Vsg[r_st * LDT + c0 + j * 8] = pv[j];
        }
        const size_t ok2 = (size_t)(2 + grp) * 64 * DH, ov2 = (size_t)(2 + grp) * 64;
#pragma unroll
        for (int j = 0; j < 4; ++j) {
            pk[j] = *(const uint4*)(gKh + ok2 + j * 8);
            pv[j] = *(const uint4*)(gVt + ov2 + j * 8);
        }
    }
    __syncthreads();

    constexpr int NSI = S / 128;  // 16 super-iterations (2 tiles each)
    for (int t = 0; t < NSI; ++t) {
        // ---- QK^T swapped: sc[qb][f] lane holds P-row q=l15, k=f*16+g*4+r ----
        f32x4 sc[2][4];
#pragma unroll
        for (int qb = 0; qb < 2; ++qb)
#pragma unroll
            for (int f = 0; f < 4; ++f) sc[qb][f] = fzero;
#pragma unroll
        for (int kk = 0; kk < 2; ++kk) {
            bf16x8 kh[4];
#pragma unroll
            for (int f = 0; f < 4; ++f)
                kh[f] = *(const bf16x8*)&Ksg[(f * 16 + l15) * LDT + kk * 32 + g * 8];
            __builtin_amdgcn_s_setprio(1);
#pragma unroll
            for (int f = 0; f < 4; ++f)
#pragma unroll
                for (int qb = 0; qb < 2; ++qb)
                    sc[qb][f] = __builtin_amdgcn_mfma_f32_16x16x32_bf16(
                        kh[f], qh_[qb][kk], sc[qb][f], 0, 0, 0);
            __builtin_amdgcn_s_setprio(0);
        }

        // ---- P = exp2(sc), truncating in-lane pack (no LDS) ----
        unsigned up[2][2][4];
#pragma unroll
        for (int qb = 0; qb < 2; ++qb)
#pragma unroll
            for (int f = 0; f < 4; ++f) {
                const int kk = f >> 1, a = f & 1;
                const unsigned e0 = __builtin_bit_cast(unsigned, exp2_fast(sc[qb][f][0]));
                const unsigned e1 = __builtin_bit_cast(unsigned, exp2_fast(sc[qb][f][1]));
                const unsigned e2 = __builtin_bit_cast(unsigned, exp2_fast(sc[qb][f][2]));
                const unsigned e3 = __builtin_bit_cast(unsigned, exp2_fast(sc[qb][f][3]));
                up[qb][kk][a * 2 + 0] = (e0 >> 16) | (e1 & 0xFFFF0000u);
                up[qb][kk][a * 2 + 1] = (e2 >> 16) | (e3 & 0xFFFF0000u);
            }

        // ---- PV + row-sum; V^T already pos-permuted globally ----
#pragma unroll
        for (int kk = 0; kk < 2; ++kk) {
            const bf16x8 pa0 = __builtin_bit_cast(bf16x8,
                make_uint4(up[0][kk][0], up[0][kk][1], up[0][kk][2], up[0][kk][3]));
            const bf16x8 pa1 = __builtin_bit_cast(bf16x8,
                make_uint4(up[1][kk][0], up[1][kk][1], up[1][kk][2], up[1][kk][3]));
            __builtin_amdgcn_s_setprio(1);
            l_acc[0] = __builtin_amdgcn_mfma_f32_16x16x32_bf16(pa0, ones, l_acc[0], 0, 0, 0);
            l_acc[1] = __builtin_amdgcn_mfma_f32_16x16x32_bf16(pa1, ones, l_acc[1], 0, 0, 0);
#pragma unroll
            for (int f = 0; f < 4; ++f) {
                const bf16x8 vt = *(const bf16x8*)&Vsg[(f * 16 + l15) * LDT + kk * 32 + g * 8];
                o_acc[0][f] = __builtin_amdgcn_mfma_f32_16x16x32_bf16(pa0, vt, o_acc[0][f], 0, 0, 0);
                o_acc[1][f] = __builtin_amdgcn_mfma_f32_16x16x32_bf16(pa1, vt, o_acc[1][f], 0, 0, 0);
            }
            __builtin_amdgcn_s_setprio(0);
        }

        __syncthreads();  // group's reads of Ksg/Vsg complete
        if (t < NSI - 1) {
#pragma unroll
            for (int j = 0; j < 4; ++j) {
                *(uint4*)&Ksg[r_st * LDT + c0 + j * 8] = pk[j];
                *(uint4*)&Vsg[r_st * LDT + c0 + j * 8] = pv[j];
            }
            if (t < NSI - 2) {
                const size_t ok = (size_t)(2 * (t + 2) + grp) * 64 * DH;
                const size_t ov = (size_t)(2 * (t + 2) + grp) * 64;
#pragma unroll
                for (int j = 0; j < 4; ++j) {
                    pk[j] = *(const uint4*)(gKh + ok + j * 8);
                    pv[j] = *(const uint4*)(gVt + ov + j * 8);
                }
            }
            __syncthreads();
        }
    }

    // ---- combine group partials via the (now dead) K/V pool ----
    float* comb  = (float*)pool;          // 2 waves x 32 rows x 64 = 16 KB
    float* lcomb = comb + 2 * 32 * 64;    // 2 waves x 32 rows
    if (grp == 1) {
#pragma unroll
        for (int qb = 0; qb < 2; ++qb)
#pragma unroll
            for (int r = 0; r < 4; ++r) {
                const int row = qb * 16 + g * 4 + r;
#pragma unroll
                for (int f = 0; f < 4; ++f)
                    comb[wq * 2048 + row * 64 + f * 16 + l15] = o_acc[qb][f][r];
                if (l15 == 0) lcomb[wq * 32 + row] = l_acc[qb][r];
            }
    }
    __syncthreads();
    if (grp == 0) {
        const int bb = bh >> 4, hh = bh & 15;
#pragma unroll
        for (int qb = 0; qb < 2; ++qb)
#pragma unroll
            for (int r = 0; r < 4; ++r) {
                const int row = qb * 16 + g * 4 + r;
                const float lsum = l_acc[qb][r] + lcomb[wq * 32 + row];
                const float inv = 1.f / lsum;
                const int srow = q0 + wq * 32 + row;
#pragma unroll
                for (int f = 0; f < 4; ++f) {
                    const float val =
                        (o_acc[qb][f][r] + comb[wq * 2048 + row * 64 + f * 16 + l15]) * inv;
                    const size_t idx = ((size_t)(bb * S + srow)) * D + hh * DH + f * 16 + l15;
                    ushort hi, lo;
                    split1(val, hi, lo);
                    AOh[idx] = hi;
                    AOl[idx] = lo;
                }
            }
    }
}

extern "C" void kernel_launch(void* const* d_in, const int* in_sizes, int n_in,
                              void* d_out, int out_size, void* d_ws, size_t ws_size,
                              hipStream_t stream) {
    (void)in_sizes; (void)n_in; (void)out_size; (void)ws_size;
    const float* q  = (const float*)d_in[0];
    const float* k  = (const float*)d_in[1];
    const float* v  = (const float*)d_in[2];
    const float* Wq = (const float*)d_in[3];
    const float* Wk = (const float*)d_in[4];
    const float* Wv = (const float*)d_in[5];
    const float* Wo = (const float*)d_in[6];
    float* out = (float*)d_out;

    uint8_t* w8 = (uint8_t*)d_ws;
    constexpr size_t MB = 1u << 20;
    ushort* Wqh = (ushort*)(w8 + 0 * MB);
    ushort* Wkh = (ushort*)(w8 + 2 * MB);
    ushort* Wvh = (ushort*)(w8 + 4 * MB);
    ushort* Woh = (ushort*)(w8 + 6 * MB);
    ushort* Wol = (ushort*)(w8 + 8 * MB);
    ushort* qbf = (ushort*)(w8 + 16 * MB);
    ushort* kbf = (ushort*)(w8 + 24 * MB);
    ushort* vbf = (ushort*)(w8 + 32 * MB);
    ushort* Qbh = (ushort*)(w8 + 40 * MB);
    ushort* Kbh = (ushort*)(w8 + 48 * MB);
    ushort* Vtb = (ushort*)(w8 + 56 * MB);
    ushort* AOh = (ushort*)(w8 + 64 * MB);
    ushort* AOl = (ushort*)(w8 + 72 * MB);

    const int n4_act = (N * D) / 4;
    const int n4_w   = (D * D) / 4;
    const dim3 blk(256);

    split_all<<<2048, blk, 0, stream>>>(
        (const float4*)q, (const float4*)k, (const float4*)v,
        (const float4*)Wq, (const float4*)Wk, (const float4*)Wv, (const float4*)Wo,
        (ushort4*)qbf, (ushort4*)kbf, (ushort4*)vbf,
        (ushort4*)Wqh, (ushort4*)Wkh, (ushort4*)Wvh,
        (ushort4*)Woh, (ushort4*)Wol,
        n4_act, n4_w);

    const float qscale = 0.125f * 1.4426950408889634f;
    gemm_qkv<<<dim3(N / 128, 24), blk, 0, stream>>>(
        qbf, kbf, vbf, Wqh, Wkh, Wvh, Qbh, Kbh, Vtb, qscale);

    attn_mfma<<<dim3(B * Hn, S / 64), blk, 0, stream>>>(
        Qbh, Kbh, Vtb, AOh, AOl);

    gemm_out<<<dim3(N / 128, D / 64), blk, 0, stream>>>(AOh, AOl, Woh, Wol, out);
}

// Round 16
// 129.393 us; speedup vs baseline: 1.8441x; 1.8441x over previous
//
#include <hip/hip_runtime.h>
#include <hip/hip_bf16.h>
#include <math.h>

namespace {
constexpr int Hn  = 16;    // heads
constexpr int DH  = 64;    // head dim
constexpr int S   = 2048;  // seq
constexpr int D   = 1024;  // model dim
constexpr int B   = 2;     // batch
constexpr int N   = B * S; // 4096 rows
}

typedef __attribute__((ext_vector_type(8))) short bf16x8;
typedef __attribute__((ext_vector_type(4))) float f32x4;

#if defined(__has_builtin)
#if __has_builtin(__builtin_amdgcn_exp2f)
#define HAVE_EXP2_BUILTIN 1
#endif
#endif

static __device__ __forceinline__ float exp2_fast(float x) {
#ifdef HAVE_EXP2_BUILTIN
    return __builtin_amdgcn_exp2f(x);
#else
    float r;
    asm("v_exp_f32 %0, %1" : "=v"(r) : "v"(x));
    return r;
#endif
}

static __device__ __forceinline__ ushort bf16rd(float x) {
    unsigned u = __builtin_bit_cast(unsigned, x);
    return (ushort)((u + 0x8000u) >> 16);
}
static __device__ __forceinline__ float bfu2f(ushort h) {
    unsigned u = (unsigned)h << 16;
    return __builtin_bit_cast(float, u);
}
static __device__ __forceinline__ void split1(float a, ushort& h, ushort& l) {
    h = bf16rd(a);
    l = bf16rd(a - bfu2f(h));
}

// async global->LDS, 16B per lane
static __device__ __forceinline__ void gload16(const ushort* g, ushort* l) {
    __builtin_amdgcn_global_load_lds((const unsigned int*)g, (unsigned int*)l, 16, 0, 0);
}

// ---------------------------------------------------------------------------
// One launch, all conversions: q,k,v -> bf16 hi; Wq,Wk,Wv -> hi; Wo -> hi/lo.
// ---------------------------------------------------------------------------
__global__ __launch_bounds__(256) void split_all(
    const float4* __restrict__ q, const float4* __restrict__ k, const float4* __restrict__ v,
    const float4* __restrict__ wq, const float4* __restrict__ wk,
    const float4* __restrict__ wv, const float4* __restrict__ wo,
    ushort4* __restrict__ qh, ushort4* __restrict__ kh, ushort4* __restrict__ vh,
    ushort4* __restrict__ wqh, ushort4* __restrict__ wkh, ushort4* __restrict__ wvh,
    ushort4* __restrict__ woh, ushort4* __restrict__ wol,
    int n4a, int n4w) {
    const int total = 3 * n4a + 4 * n4w;
    const int stride = gridDim.x * 256;
    for (int i = blockIdx.x * 256 + threadIdx.x; i < total; i += stride) {
        if (i < 3 * n4a) {
            const int which = i / n4a;
            const int j = i - which * n4a;
            const float4 val = (which == 0 ? q : which == 1 ? k : v)[j];
            ushort4* ph = which == 0 ? qh : which == 1 ? kh : vh;
            ph[j] = make_ushort4(bf16rd(val.x), bf16rd(val.y), bf16rd(val.z), bf16rd(val.w));
        } else {
            const int t = i - 3 * n4a;
            const int which = t / n4w;
            const int j = t - which * n4w;
            const float4 val = (which == 0 ? wq : which == 1 ? wk : which == 2 ? wv : wo)[j];
            if (which == 3) {
                ushort4 hh, ll;
                split1(val.x, hh.x, ll.x);
                split1(val.y, hh.y, ll.y);
                split1(val.z, hh.z, ll.z);
                split1(val.w, hh.w, ll.w);
                woh[j] = hh;
                wol[j] = ll;
            } else {
                ushort4* ph = which == 0 ? wqh : which == 1 ? wkh : wvh;
                ph[j] = make_ushort4(bf16rd(val.x), bf16rd(val.y), bf16rd(val.z), bf16rd(val.w));
            }
        }
    }
}

// ---------------------------------------------------------------------------
// Merged Q/K/V projection (r10-verified): 1-pass bf16, BK=64, single LDS
// buffer, global_load_lds staging (pre-swizzled source, swizzled ds_read),
// 2 barriers per K-step. Grid 32 x 24; which: 0->Q(scaled) 1->K 2->V^T.
// V^T store applies the pos<->kv permutation (kv=16a+4g+r -> pos=8g+4a+r).
// ---------------------------------------------------------------------------
__global__ __launch_bounds__(256) void gemm_qkv(
    const ushort* __restrict__ qbf, const ushort* __restrict__ kbf,
    const ushort* __restrict__ vbf,
    const ushort* __restrict__ Wqh, const ushort* __restrict__ Wkh,
    const ushort* __restrict__ Wvh,
    ushort* __restrict__ Qbh, ushort* __restrict__ Kbh,
    ushort* __restrict__ Vtb, float qscale) {
    constexpr int BK = 64;   // 128 B rows, 8 chunks of 16 B
    constexpr int K = D;
    __shared__ __align__(16) ushort sA[128 * BK];
    __shared__ __align__(16) ushort sB[128 * BK];

    const int tid = threadIdx.x;
    const int which = blockIdx.y >> 3;
    const int m0 = blockIdx.x * 128;
    const int n0 = (blockIdx.y & 7) * 128;

    const ushort* A = which == 0 ? qbf : which == 1 ? kbf : vbf;
    const ushort* W = which == 0 ? Wqh : which == 1 ? Wkh : Wvh;

    const int l  = tid & 63;
    const int w  = tid >> 6;
    const int wm = w >> 1, wn = w & 1;
    const int lm = l & 15, g = l >> 4;

    const int srow = l >> 3;                 // 0..7
    const int schunk = (l & 7) ^ srow;       // pre-swizzled source chunk
    const ushort* gA = A + (size_t)(m0 + w * 32 + srow) * K + schunk * 8;
    const ushort* gB = W + (size_t)(n0 + w * 32 + srow) * K + schunk * 8;
    ushort* lA = &sA[(w * 32) * BK];
    ushort* lB = &sB[(w * 32) * BK];

    const f32x4 fzero = {0.f, 0.f, 0.f, 0.f};
    f32x4 acc[4][4];
#pragma unroll
    for (int mi = 0; mi < 4; ++mi)
#pragma unroll
        for (int ni = 0; ni < 4; ++ni) acc[mi][ni] = fzero;

    const int rsw = lm & 7;  // read-side swizzle

    for (int s = 0; s < K / BK; ++s) {
        const int k0 = s * BK;
        if (s) __syncthreads();
#pragma unroll
        for (int j = 0; j < 4; ++j) {
            gload16(gA + (size_t)(j * 8) * K + k0, lA + (j * 8) * BK);
            gload16(gB + (size_t)(j * 8) * K + k0, lB + (j * 8) * BK);
        }
        __syncthreads();

#pragma unroll
        for (int kk = 0; kk < 2; ++kk) {
            bf16x8 ah[4], bh[4];
#pragma unroll
            for (int mi = 0; mi < 4; ++mi)
                ah[mi] = *(const bf16x8*)&sA[(wm * 64 + mi * 16 + lm) * BK + (((kk * 4 + g) ^ rsw) * 8)];
#pragma unroll
            for (int ni = 0; ni < 4; ++ni)
                bh[ni] = *(const bf16x8*)&sB[(wn * 64 + ni * 16 + lm) * BK + (((kk * 4 + g) ^ rsw) * 8)];
            __builtin_amdgcn_s_setprio(1);
#pragma unroll
            for (int mi = 0; mi < 4; ++mi)
#pragma unroll
                for (int ni = 0; ni < 4; ++ni)
                    acc[mi][ni] = __builtin_amdgcn_mfma_f32_16x16x32_bf16(
                        ah[mi], bh[ni], acc[mi][ni], 0, 0, 0);
            __builtin_amdgcn_s_setprio(0);
        }
    }

#pragma unroll
    for (int mi = 0; mi < 4; ++mi)
#pragma unroll
        for (int ni = 0; ni < 4; ++ni) {
            const int col = n0 + wn * 64 + ni * 16 + lm;
            const int rbase = m0 + wm * 64 + mi * 16 + g * 4;
            const int hh = col >> 6, dh = col & (DH - 1);
            if (which == 0) {  // Q: scaled, hi
#pragma unroll
                for (int r = 0; r < 4; ++r) {
                    const int row = rbase + r;
                    const int bb = row >> 11, ss = row & (S - 1);
                    const size_t idx = (((size_t)(bb * Hn + hh)) * S + ss) * DH + dh;
                    Qbh[idx] = bf16rd(acc[mi][ni][r] * qscale);
                }
            } else if (which == 1) {  // K: hi
#pragma unroll
                for (int r = 0; r < 4; ++r) {
                    const int row = rbase + r;
                    const int bb = row >> 11, ss = row & (S - 1);
                    const size_t idx = (((size_t)(bb * Hn + hh)) * S + ss) * DH + dh;
                    Kbh[idx] = bf16rd(acc[mi][ni][r]);
                }
            } else {  // V^T: hi, transposed + pos-permuted store
                const int bb = rbase >> 11, ss = rbase & (S - 1);
                const int ssp = (ss & ~31) | (((ss >> 2) & 3) << 3) | (((ss >> 4) & 1) << 2);
                ushort4 pk;
                pk.x = bf16rd(acc[mi][ni][0]);
                pk.y = bf16rd(acc[mi][ni][1]);
                pk.z = bf16rd(acc[mi][ni][2]);
                pk.w = bf16rd(acc[mi][ni][3]);
                const size_t idx = (((size_t)(bb * Hn + hh)) * DH + dh) * S + ssp;
                *(ushort4*)&Vtb[idx] = pk;
            }
        }
}

// ---------------------------------------------------------------------------
// Output projection GEMM (r14-passed): 3-pass split-bf16, fp32 store,
// gload_lds staging BK=64 (pre-swizzled source + swizzled b128 reads),
// single 48 KB LDS buffer, 2 barriers per K-step, 48 MFMA/step/wave.
// ---------------------------------------------------------------------------
__global__ __launch_bounds__(256) void gemm_out(const ushort* __restrict__ Ah,
                                                const ushort* __restrict__ Al,
                                                const ushort* __restrict__ Wh,
                                                const ushort* __restrict__ Wl,
                                                float* __restrict__ C) {
    constexpr int BK = 64;
    constexpr int K = D, O = D;
    __shared__ __align__(16) ushort sAh[128 * BK];
    __shared__ __align__(16) ushort sAl[128 * BK];
    __shared__ __align__(16) ushort sBh[64 * BK];
    __shared__ __align__(16) ushort sBl[64 * BK];

    const int tid = threadIdx.x;
    const int m0 = blockIdx.x * 128;
    const int n0 = blockIdx.y * 64;

    const int l  = tid & 63;
    const int w  = tid >> 6;
    const int wm = w >> 1, wn = w & 1;
    const int lm = l & 15, g = l >> 4;

    const int srow = l >> 3;
    const int schunk = (l & 7) ^ srow;
    const ushort* gAh = Ah + (size_t)(m0 + w * 32 + srow) * K + schunk * 8;
    const ushort* gAl = Al + (size_t)(m0 + w * 32 + srow) * K + schunk * 8;
    const ushort* gBh = Wh + (size_t)(n0 + w * 16 + srow) * K + schunk * 8;
    const ushort* gBl = Wl + (size_t)(n0 + w * 16 + srow) * K + schunk * 8;
    ushort* lAh = &sAh[(w * 32) * BK];
    ushort* lAl = &sAl[(w * 32) * BK];
    ushort* lBh = &sBh[(w * 16) * BK];
    ushort* lBl = &sBl[(w * 16) * BK];

    const f32x4 fzero = {0.f, 0.f, 0.f, 0.f};
    f32x4 acc[4][2];
#pragma unroll
    for (int mi = 0; mi < 4; ++mi)
#pragma unroll
        for (int ni = 0; ni < 2; ++ni) acc[mi][ni] = fzero;

    const int rsw = lm & 7;

    for (int s = 0; s < K / BK; ++s) {
        const int k0 = s * BK;
        if (s) __syncthreads();
#pragma unroll
        for (int j = 0; j < 4; ++j) {
            gload16(gAh + (size_t)(j * 8) * K + k0, lAh + (j * 8) * BK);
            gload16(gAl + (size_t)(j * 8) * K + k0, lAl + (j * 8) * BK);
        }
#pragma unroll
        for (int j = 0; j < 2; ++j) {
            gload16(gBh + (size_t)(j * 8) * K + k0, lBh + (j * 8) * BK);
            gload16(gBl + (size_t)(j * 8) * K + k0, lBl + (j * 8) * BK);
        }
        __syncthreads();

#pragma unroll
        for (int kk = 0; kk < 2; ++kk) {
            const int rc = ((kk * 4 + g) ^ rsw) * 8;
            bf16x8 ah[4], al[4], bh[2], bl[2];
#pragma unroll
            for (int mi = 0; mi < 4; ++mi) {
                const int row = wm * 64 + mi * 16 + lm;
                ah[mi] = *(const bf16x8*)&sAh[row * BK + rc];
                al[mi] = *(const bf16x8*)&sAl[row * BK + rc];
            }
#pragma unroll
            for (int ni = 0; ni < 2; ++ni) {
                const int rowb = wn * 32 + ni * 16 + lm;
                bh[ni] = *(const bf16x8*)&sBh[rowb * BK + rc];
                bl[ni] = *(const bf16x8*)&sBl[rowb * BK + rc];
            }
            __builtin_amdgcn_s_setprio(1);
#pragma unroll
            for (int mi = 0; mi < 4; ++mi)
#pragma unroll
                for (int ni = 0; ni < 2; ++ni) {
                    acc[mi][ni] = __builtin_amdgcn_mfma_f32_16x16x32_bf16(
                        al[mi], bh[ni], acc[mi][ni], 0, 0, 0);
                    acc[mi][ni] = __builtin_amdgcn_mfma_f32_16x16x32_bf16(
                        ah[mi], bl[ni], acc[mi][ni], 0, 0, 0);
                    acc[mi][ni] = __builtin_amdgcn_mfma_f32_16x16x32_bf16(
                        ah[mi], bh[ni], acc[mi][ni], 0, 0, 0);
                }
            __builtin_amdgcn_s_setprio(0);
        }
    }

#pragma unroll
    for (int mi = 0; mi < 4; ++mi)
#pragma unroll
        for (int ni = 0; ni < 2; ++ni) {
            const int col = n0 + wn * 32 + ni * 16 + lm;
            const int rbase = m0 + wm * 64 + mi * 16 + g * 4;
#pragma unroll
            for (int r = 0; r < 4; ++r)
                C[(size_t)(rbase + r) * O + col] = acc[mi][ni][r];
        }
}

// ---------------------------------------------------------------------------
// Split-KV MFMA flash attention with IN-REGISTER P (r13 math). RACE FIX:
// the group-combine no longer aliases the K/V LDS pool — it uses dedicated
// LDS buffers, so the last tile's MFMA ds_reads can never race the combine
// writes. 512 thr = 8 waves: waves 0-3 even KV tiles, 4-7 odd.
// LDS = 36.9 KB pool + 33 KB combine = 70.1 KB (2 blocks/CU, as before).
// ---------------------------------------------------------------------------
__global__ __launch_bounds__(512) void attn_mfma(const ushort* __restrict__ Qbh,
                                                 const ushort* __restrict__ Kbh,
                                                 const ushort* __restrict__ Vt,
                                                 ushort* __restrict__ AOh,
                                                 ushort* __restrict__ AOl) {
    constexpr int LDT = 72;
    __shared__ __align__(16) ushort pool[4 * 64 * LDT];  // 36,864 B (K/V only)
    __shared__ __align__(16) float comb[4 * 32 * 64];    // 32,768 B (combine)
    __shared__ float lcomb[4 * 32];                      // 512 B

    const int tid = threadIdx.x;
    const int l = tid & 63, w = tid >> 6;   // w 0..7
    const int wq = w & 3, grp = w >> 2;     // q-wave slot, kv parity group
    const int g = l >> 4, l15 = l & 15;
    const int bh = blockIdx.x;
    const int q0 = blockIdx.y * 128;
    const size_t bhb = (size_t)bh * S * DH;

    ushort* Ksg = pool + grp * (64 * LDT);
    ushort* Vsg = pool + (2 + grp) * (64 * LDT);

    // Q fragments (log2e/8 folded in at projection); rows q0 + wq*32 + ...
    bf16x8 qh_[2][2];
#pragma unroll
    for (int qb = 0; qb < 2; ++qb)
#pragma unroll
        for (int kk = 0; kk < 2; ++kk) {
            const size_t idx = bhb + (size_t)(q0 + wq * 32 + qb * 16 + l15) * DH + kk * 32 + g * 8;
            qh_[qb][kk] = *(const bf16x8*)(Qbh + idx);
        }

    // staging: each group (256 threads) stages its own tile stream
    const int t8 = tid & 255;
    const int r_st = t8 >> 2;
    const int c0 = (t8 & 3) * 16;
    const ushort* gKh = Kbh + bhb + (size_t)r_st * DH + c0;
    const ushort* gVt = Vt + (size_t)bh * DH * S + (size_t)r_st * S + c0;

    const f32x4 fzero = {0.f, 0.f, 0.f, 0.f};
    f32x4 o_acc[2][4];
    f32x4 l_acc[2];
#pragma unroll
    for (int qb = 0; qb < 2; ++qb) {
        l_acc[qb] = fzero;
#pragma unroll
        for (int f = 0; f < 4; ++f) o_acc[qb][f] = fzero;
    }

    bf16x8 ones;
#pragma unroll
    for (int i = 0; i < 8; ++i) ones[i] = (short)0x3F80;

    // prologue: tile grp -> LDS; tile 2+grp -> regs
    uint4 pk0, pk1, pv0, pv1;
    {
        const size_t ok = (size_t)grp * 64 * DH, ov = (size_t)grp * 64;
        pk0 = *(const uint4*)(gKh + ok); pk1 = *(const uint4*)(gKh + ok + 8);
        pv0 = *(const uint4*)(gVt + ov); pv1 = *(const uint4*)(gVt + ov + 8);
        *(uint4*)&Ksg[r_st * LDT + c0]     = pk0;
        *(uint4*)&Ksg[r_st * LDT + c0 + 8] = pk1;
        *(uint4*)&Vsg[r_st * LDT + c0]     = pv0;
        *(uint4*)&Vsg[r_st * LDT + c0 + 8] = pv1;
        const size_t ok2 = (size_t)(2 + grp) * 64 * DH, ov2 = (size_t)(2 + grp) * 64;
        pk0 = *(const uint4*)(gKh + ok2); pk1 = *(const uint4*)(gKh + ok2 + 8);
        pv0 = *(const uint4*)(gVt + ov2); pv1 = *(const uint4*)(gVt + ov2 + 8);
    }
    __syncthreads();

    constexpr int NSI = S / 128;  // 16 super-iterations (2 tiles each)
    for (int t = 0; t < NSI; ++t) {
        // ---- QK^T swapped: sc[qb][f] lane holds P-row q=l15, k=f*16+g*4+r ----
        f32x4 sc[2][4];
#pragma unroll
        for (int qb = 0; qb < 2; ++qb)
#pragma unroll
            for (int f = 0; f < 4; ++f) sc[qb][f] = fzero;
#pragma unroll
        for (int kk = 0; kk < 2; ++kk) {
            bf16x8 kh[4];
#pragma unroll
            for (int f = 0; f < 4; ++f)
                kh[f] = *(const bf16x8*)&Ksg[(f * 16 + l15) * LDT + kk * 32 + g * 8];
            __builtin_amdgcn_s_setprio(1);
#pragma unroll
            for (int f = 0; f < 4; ++f)
#pragma unroll
                for (int qb = 0; qb < 2; ++qb)
                    sc[qb][f] = __builtin_amdgcn_mfma_f32_16x16x32_bf16(
                        kh[f], qh_[qb][kk], sc[qb][f], 0, 0, 0);
            __builtin_amdgcn_s_setprio(0);
        }

        // ---- P = exp2(sc), truncating in-lane pack (no LDS) ----
        // pos map within kk-block: pos=8g+4a+r <-> kv=16a+4g+r (a=f&1)
        unsigned up[2][2][4];
#pragma unroll
        for (int qb = 0; qb < 2; ++qb)
#pragma unroll
            for (int f = 0; f < 4; ++f) {
                const int kk = f >> 1, a = f & 1;
                const unsigned e0 = __builtin_bit_cast(unsigned, exp2_fast(sc[qb][f][0]));
                const unsigned e1 = __builtin_bit_cast(unsigned, exp2_fast(sc[qb][f][1]));
                const unsigned e2 = __builtin_bit_cast(unsigned, exp2_fast(sc[qb][f][2]));
                const unsigned e3 = __builtin_bit_cast(unsigned, exp2_fast(sc[qb][f][3]));
                up[qb][kk][a * 2 + 0] = (e0 >> 16) | (e1 & 0xFFFF0000u);
                up[qb][kk][a * 2 + 1] = (e2 >> 16) | (e3 & 0xFFFF0000u);
            }

        // ---- PV + row-sum; V^T already pos-permuted globally ----
#pragma unroll
        for (int kk = 0; kk < 2; ++kk) {
            const bf16x8 pa0 = __builtin_bit_cast(bf16x8,
                make_uint4(up[0][kk][0], up[0][kk][1], up[0][kk][2], up[0][kk][3]));
            const bf16x8 pa1 = __builtin_bit_cast(bf16x8,
                make_uint4(up[1][kk][0], up[1][kk][1], up[1][kk][2], up[1][kk][3]));
            __builtin_amdgcn_s_setprio(1);
            l_acc[0] = __builtin_amdgcn_mfma_f32_16x16x32_bf16(pa0, ones, l_acc[0], 0, 0, 0);
            l_acc[1] = __builtin_amdgcn_mfma_f32_16x16x32_bf16(pa1, ones, l_acc[1], 0, 0, 0);
#pragma unroll
            for (int f = 0; f < 4; ++f) {
                const bf16x8 vt = *(const bf16x8*)&Vsg[(f * 16 + l15) * LDT + kk * 32 + g * 8];
                o_acc[0][f] = __builtin_amdgcn_mfma_f32_16x16x32_bf16(pa0, vt, o_acc[0][f], 0, 0, 0);
                o_acc[1][f] = __builtin_amdgcn_mfma_f32_16x16x32_bf16(pa1, vt, o_acc[1][f], 0, 0, 0);
            }
            __builtin_amdgcn_s_setprio(0);
        }

        __syncthreads();  // group's reads of Ksg/Vsg complete
        if (t < NSI - 1) {
            *(uint4*)&Ksg[r_st * LDT + c0]     = pk0;
            *(uint4*)&Ksg[r_st * LDT + c0 + 8] = pk1;
            *(uint4*)&Vsg[r_st * LDT + c0]     = pv0;
            *(uint4*)&Vsg[r_st * LDT + c0 + 8] = pv1;
            if (t < NSI - 2) {
                const size_t ok = (size_t)(2 * (t + 2) + grp) * 64 * DH;
                const size_t ov = (size_t)(2 * (t + 2) + grp) * 64;
                pk0 = *(const uint4*)(gKh + ok); pk1 = *(const uint4*)(gKh + ok + 8);
                pv0 = *(const uint4*)(gVt + ov); pv1 = *(const uint4*)(gVt + ov + 8);
            }
            __syncthreads();
        }
    }

    // ---- combine group partials via DEDICATED LDS (no pool aliasing) ----
    if (grp == 1) {
#pragma unroll
        for (int qb = 0; qb < 2; ++qb)
#pragma unroll
            for (int r = 0; r < 4; ++r) {
                const int row = qb * 16 + g * 4 + r;
#pragma unroll
                for (int f = 0; f < 4; ++f)
                    comb[wq * 2048 + row * 64 + f * 16 + l15] = o_acc[qb][f][r];
                if (l15 == 0) lcomb[wq * 32 + row] = l_acc[qb][r];
            }
    }
    __syncthreads();
    if (grp == 0) {
        const int bb = bh >> 4, hh = bh & 15;
#pragma unroll
        for (int qb = 0; qb < 2; ++qb)
#pragma unroll
            for (int r = 0; r < 4; ++r) {
                const int row = qb * 16 + g * 4 + r;
                const float lsum = l_acc[qb][r] + lcomb[wq * 32 + row];
                const float inv = 1.f / lsum;
                const int srow = q0 + wq * 32 + row;
#pragma unroll
                for (int f = 0; f < 4; ++f) {
                    const float val =
                        (o_acc[qb][f][r] + comb[wq * 2048 + row * 64 + f * 16 + l15]) * inv;
                    const size_t idx = ((size_t)(bb * S + srow)) * D + hh * DH + f * 16 + l15;
                    ushort hi, lo;
                    split1(val, hi, lo);
                    AOh[idx] = hi;
                    AOl[idx] = lo;
                }
            }
    }
}

extern "C" void kernel_launch(void* const* d_in, const int* in_sizes, int n_in,
                              void* d_out, int out_size, void* d_ws, size_t ws_size,
                              hipStream_t stream) {
    (void)in_sizes; (void)n_in; (void)out_size; (void)ws_size;
    const float* q  = (const float*)d_in[0];
    const float* k  = (const float*)d_in[1];
    const float* v  = (const float*)d_in[2];
    const float* Wq = (const float*)d_in[3];
    const float* Wk = (const float*)d_in[4];
    const float* Wv = (const float*)d_in[5];
    const float* Wo = (const float*)d_in[6];
    float* out = (float*)d_out;

    uint8_t* w8 = (uint8_t*)d_ws;
    constexpr size_t MB = 1u << 20;
    ushort* Wqh = (ushort*)(w8 + 0 * MB);
    ushort* Wkh = (ushort*)(w8 + 2 * MB);
    ushort* Wvh = (ushort*)(w8 + 4 * MB);
    ushort* Woh = (ushort*)(w8 + 6 * MB);
    ushort* Wol = (ushort*)(w8 + 8 * MB);
    ushort* qbf = (ushort*)(w8 + 16 * MB);
    ushort* kbf = (ushort*)(w8 + 24 * MB);
    ushort* vbf = (ushort*)(w8 + 32 * MB);
    ushort* Qbh = (ushort*)(w8 + 40 * MB);
    ushort* Kbh = (ushort*)(w8 + 48 * MB);
    ushort* Vtb = (ushort*)(w8 + 56 * MB);
    ushort* AOh = (ushort*)(w8 + 64 * MB);
    ushort* AOl = (ushort*)(w8 + 72 * MB);

    const int n4_act = (N * D) / 4;
    const int n4_w   = (D * D) / 4;
    const dim3 blk(256);

    split_all<<<2048, blk, 0, stream>>>(
        (const float4*)q, (const float4*)k, (const float4*)v,
        (const float4*)Wq, (const float4*)Wk, (const float4*)Wv, (const float4*)Wo,
        (ushort4*)qbf, (ushort4*)kbf, (ushort4*)vbf,
        (ushort4*)Wqh, (ushort4*)Wkh, (ushort4*)Wvh,
        (ushort4*)Woh, (ushort4*)Wol,
        n4_act, n4_w);

    const float qscale = 0.125f * 1.4426950408889634f;
    gemm_qkv<<<dim3(N / 128, 24), blk, 0, stream>>>(
        qbf, kbf, vbf, Wqh, Wkh, Wvh, Qbh, Kbh, Vtb, qscale);

    attn_mfma<<<dim3(B * Hn, S / 128), dim3(512), 0, stream>>>(
        Qbh, Kbh, Vtb, AOh, AOl);

    gemm_out<<<dim3(N / 128, D / 64), blk, 0, stream>>>(AOh, AOl, Woh, Wol, out);
}